// Round 12
// baseline (522.802 us; speedup 1.0000x reference)
//
#include <hip/hip_runtime.h>
#include <math.h>

#define NPTS 8192
#define KNN 20
#define NLISTS 32     // partial lists per row = blockIdx.y count of knnA

// workspace layout in floats
#define OFF_SQ   0          // 8192
#define OFF_A    172032     // 8192*64 (featAB A; region reused for W packs in MLP phase)
#define OFF_B    696320     // 8192*64
#define OFF_CAT  1220608    // 8192*192 fp32
#define OFF_H1   2793472    // region: kNN part+packs during convs; h1 split-bf16 in MLP phase
#define OFF_H2   11182080   // region: cat split-bf16 during convs/gemm1; h2 split-bf16 after
#define OFF_H3   13279232   // 8192*128 fp32
#define OFF_PART OFF_H1                       // 8192*32*20 u32 = 5242880 slots
#define OFF_PACK (OFF_H1 + 5242880)           // 4 arrays x 262144 float-slots (bf16 [8192][64])
#define PACK_ELEMS 262144
#define OFF_WT   OFF_A                        // W packs (491520 float-slots), after conv3

typedef __attribute__((ext_vector_type(8))) short bf16x8;
typedef __attribute__((ext_vector_type(16))) float f32x16;

__device__ inline unsigned umed3(unsigned a, unsigned b, unsigned c) {
    unsigned d;
    asm("v_med3_u32 %0, %1, %2, %3" : "=v"(d) : "v"(a), "v"(b), "v"(c));
    return d;
}

__device__ inline unsigned short f2bf(float f) {   // round-to-nearest-even bf16
    unsigned u = __float_as_uint(f);
    u += 0x7FFFu + ((u >> 16) & 1u);
    return (unsigned short)(u >> 16);
}

__device__ inline void tsplit(float x, unsigned short& hi, unsigned short& lo) {
    unsigned u = __float_as_uint(x);
    hi = (unsigned short)(u >> 16);
    float d = x - __uint_as_float(u & 0xFFFF0000u);
    lo = (unsigned short)(__float_as_uint(d) >> 16);
}

// ---------------- setup: conv1 prepack (blocks 0..255) + sqnorm (blocks 256..287) ----
__global__ __launch_bounds__(256)
void setup_kernel(const float* __restrict__ x, float* __restrict__ sq,
                  unsigned short* __restrict__ Xhi, unsigned short* __restrict__ Xlo,
                  unsigned short* __restrict__ Yhi, unsigned short* __restrict__ Ylo) {
    const int b = blockIdx.x;
    if (b < 256) {
        int t = (b * 256 + threadIdx.x) * 2;      // over NPTS*16
        int n = t >> 4, k = t & 15;
        float xv[2];
        xv[0] = (k < 3) ? x[(size_t)n * 3 + k] : 0.f;
        xv[1] = (k + 1 < 3) ? x[(size_t)n * 3 + k + 1] : 0.f;
        ushort2 hx, lx, hy, ly;
        unsigned short* hxp = (unsigned short*)&hx;
        unsigned short* lxp = (unsigned short*)&lx;
        unsigned short* hyp = (unsigned short*)&hy;
        unsigned short* lyp = (unsigned short*)&ly;
        #pragma unroll
        for (int e = 0; e < 2; ++e) {
            float xx = xv[e];
            unsigned short hi = f2bf(xx);
            float hif = __uint_as_float((unsigned)hi << 16);
            unsigned short lo = f2bf(xx - hif);
            float y = -2.f * xx;
            unsigned short yhi = f2bf(y);
            float yhif = __uint_as_float((unsigned)yhi << 16);
            unsigned short ylo = f2bf(y - yhif);
            hxp[e] = hi; lxp[e] = lo; hyp[e] = yhi; lyp[e] = ylo;
        }
        *(ushort2*)&Xhi[t] = hx;
        *(ushort2*)&Xlo[t] = lx;
        *(ushort2*)&Yhi[t] = hy;
        *(ushort2*)&Ylo[t] = ly;
    } else {
        int n = (b - 256) * 256 + threadIdx.x;
        float a = x[(size_t)n * 3], bb = x[(size_t)n * 3 + 1], c = x[(size_t)n * 3 + 2];
        sq[n] = fmaf(a, a, fmaf(bb, bb, c * c));
    }
}

// ---------------- fused W prepack: W[K][N] fp32 -> [N][K] split-bf16, 3 matrices ----
__global__ __launch_bounds__(256)
void wprep_kernel(const float* __restrict__ Wl, const float* __restrict__ Wm1,
                  const float* __restrict__ Wm2,
                  unsigned short* __restrict__ WlT_hi, unsigned short* __restrict__ WlT_lo,
                  unsigned short* __restrict__ Wm1T_hi, unsigned short* __restrict__ Wm1T_lo,
                  unsigned short* __restrict__ Wm2T_hi, unsigned short* __restrict__ Wm2T_lo) {
    const int b = blockIdx.x;
    const float* W; unsigned short *Thi, *Tlo; int t, K, nmask, nbits;
    if (b < 768)       { W = Wl;  Thi = WlT_hi;  Tlo = WlT_lo;  t = b * 256 + threadIdx.x;          K = 192;  nbits = 10; }
    else if (b < 1792) { W = Wm1; Thi = Wm1T_hi; Tlo = Wm1T_lo; t = (b - 768) * 256 + threadIdx.x;  K = 1024; nbits = 8; }
    else               { W = Wm2; Thi = Wm2T_hi; Tlo = Wm2T_lo; t = (b - 1792) * 256 + threadIdx.x; K = 256;  nbits = 7; }
    nmask = (1 << nbits) - 1;
    int k = t >> nbits, n = t & nmask;
    float xx = W[t];
    unsigned short hi = f2bf(xx);
    float hif = __uint_as_float((unsigned)hi << 16);
    unsigned short lo = f2bf(xx - hif);
    Thi[(size_t)n * K + k] = hi;
    Tlo[(size_t)n * K + k] = lo;
}

// sorted-insert network on a NAMED key (rule #20: no address-taking)
#define NET(key)                                                               \
    do {                                                                       \
        _Pragma("unroll")                                                      \
        for (int p = KNN - 1; p >= 1; --p)                                     \
            top[p] = umed3(key, top[p - 1], top[p]);                           \
        top[0] = min(top[0], key);                                             \
    } while (0)

// candidate processing WITHOUT self-exclusion (j != bi guaranteed for this tile)
#define PROCESS_NX(Cv, j0base)                                                 \
    do {                                                                       \
        _Pragma("unroll")                                                      \
        for (int q = 0; q < 4; ++q) {                                          \
            _Pragma("unroll")                                                  \
            for (int t = 0; t < 4; ++t) {                                      \
                const int j = (j0base) + h * 4 + q * 8 + t;                    \
                float dd = fmaxf((Cv)[q * 4 + t], 0.f);                        \
                unsigned key = (__float_as_uint(dd) & 0xFFFFE000u) | (unsigned)j; \
                NET(key);                                                      \
            }                                                                  \
        }                                                                      \
    } while (0)

// candidate processing WITH self-exclusion (tile contains j == bi)
#define PROCESS_EX(Cv, j0base)                                                 \
    do {                                                                       \
        _Pragma("unroll")                                                      \
        for (int q = 0; q < 4; ++q) {                                          \
            _Pragma("unroll")                                                  \
            for (int t = 0; t < 4; ++t) {                                      \
                const int j = (j0base) + h * 4 + q * 8 + t;                    \
                float dd = fmaxf((Cv)[q * 4 + t], 0.f);                        \
                unsigned key = (__float_as_uint(dd) & 0xFFFFE000u) | (unsigned)j; \
                if (j == bi) key = 0xFFFFFFFFu;                                \
                NET(key);                                                      \
            }                                                                  \
        }                                                                      \
    } while (0)

#define PROCESS_SEL(Cv, j0base)                                                \
    do {                                                                       \
        if ((j0base) == myTile) PROCESS_EX(Cv, j0base);                        \
        else                    PROCESS_NX(Cv, j0base);                        \
    } while (0)

// ---------------- kNN phase A via MFMA + featAB tail ----------------
// Grid (64, 32). Pipeline as r10. Self-exclusion hoisted to a wave-uniform
// per-tile branch (fires in 1/32 of blocks). Tail: each wave computes one
// featAB row (A = X*W_top, B = X*W_bot) — hides featAB's serial launch.
template<int KP, int D>
__global__ __launch_bounds__(256, 2)
void knnA_mfma(const unsigned short* __restrict__ Yhi, const unsigned short* __restrict__ Ylo,
               const unsigned short* __restrict__ Xhi, const unsigned short* __restrict__ Xlo,
               const float* __restrict__ sq, unsigned int* __restrict__ part,
               const float* __restrict__ Xf, int stride, const float* __restrict__ W,
               float* __restrict__ A, float* __restrict__ B) {
    constexpr int NS = KP / 16;
    constexpr int NT = 8;
    const int wave = threadIdx.x >> 6, lane = threadIdx.x & 63;
    const int col = lane & 31;
    const int h   = lane >> 5;
    const int bi  = (blockIdx.x * 4 + wave) * 32 + col;
    const int myTile = bi - col;          // wave-uniform: the only tile that can contain j==bi
    const int jbase = blockIdx.y * 256;

    bf16x8 bhi[NS], blo[NS];
    #pragma unroll
    for (int s = 0; s < NS; ++s) {
        bhi[s] = *(const bf16x8*)&Xhi[(size_t)bi * KP + s * 16 + h * 8];
        blo[s] = *(const bf16x8*)&Xlo[(size_t)bi * KP + s * 16 + h * 8];
    }
    const float sqi = sq[bi];

    unsigned top[KNN];
    #pragma unroll
    for (int k = 0; k < KNN; ++k) top[k] = 0xFFFFFFFFu;

    bf16x8 fA[NS], fB[NS], lo[NS];
    f32x16 CCa, CCb;

    {
        const size_t a0 = (size_t)(jbase + col) * KP + h * 8;
        #pragma unroll
        for (int s = 0; s < NS; ++s)
            fA[s] = *(const bf16x8*)&Yhi[a0 + s * 16];
    }

    #pragma unroll 1
    for (int jt2 = 0; jt2 < NT; jt2 += 2) {
        const int j0 = jbase + jt2 * 32;
        const int aj = j0 + col;

        #pragma unroll
        for (int s = 0; s < NS; ++s)
            fB[s] = *(const bf16x8*)&Yhi[(size_t)(aj + 32) * KP + s * 16 + h * 8];
        #pragma unroll
        for (int s = 0; s < NS; ++s)
            lo[s] = *(const bf16x8*)&Ylo[(size_t)aj * KP + s * 16 + h * 8];
        float4 e0 = *(const float4*)&sq[j0 + h * 4];
        float4 e1 = *(const float4*)&sq[j0 + h * 4 + 8];
        float4 e2 = *(const float4*)&sq[j0 + h * 4 + 16];
        float4 e3 = *(const float4*)&sq[j0 + h * 4 + 24];

        if (jt2 > 0) PROCESS_SEL(CCb, j0 - 32);

        CCa[0] = sqi + e0.x; CCa[1] = sqi + e0.y; CCa[2]  = sqi + e0.z; CCa[3]  = sqi + e0.w;
        CCa[4] = sqi + e1.x; CCa[5] = sqi + e1.y; CCa[6]  = sqi + e1.z; CCa[7]  = sqi + e1.w;
        CCa[8] = sqi + e2.x; CCa[9] = sqi + e2.y; CCa[10] = sqi + e2.z; CCa[11] = sqi + e2.w;
        CCa[12] = sqi + e3.x; CCa[13] = sqi + e3.y; CCa[14] = sqi + e3.z; CCa[15] = sqi + e3.w;
        #pragma unroll
        for (int s = 0; s < NS; ++s) {
            CCa = __builtin_amdgcn_mfma_f32_32x32x16_bf16(fA[s], bhi[s], CCa, 0, 0, 0);
            CCa = __builtin_amdgcn_mfma_f32_32x32x16_bf16(fA[s], blo[s], CCa, 0, 0, 0);
            CCa = __builtin_amdgcn_mfma_f32_32x32x16_bf16(lo[s], bhi[s], CCa, 0, 0, 0);
        }

        if (jt2 + 2 < NT) {
            #pragma unroll
            for (int s = 0; s < NS; ++s)
                fA[s] = *(const bf16x8*)&Yhi[(size_t)(aj + 64) * KP + s * 16 + h * 8];
        }
        #pragma unroll
        for (int s = 0; s < NS; ++s)
            lo[s] = *(const bf16x8*)&Ylo[(size_t)(aj + 32) * KP + s * 16 + h * 8];
        float4 o0 = *(const float4*)&sq[j0 + 32 + h * 4];
        float4 o1 = *(const float4*)&sq[j0 + 32 + h * 4 + 8];
        float4 o2 = *(const float4*)&sq[j0 + 32 + h * 4 + 16];
        float4 o3 = *(const float4*)&sq[j0 + 32 + h * 4 + 24];

        PROCESS_SEL(CCa, j0);

        CCb[0] = sqi + o0.x; CCb[1] = sqi + o0.y; CCb[2]  = sqi + o0.z; CCb[3]  = sqi + o0.w;
        CCb[4] = sqi + o1.x; CCb[5] = sqi + o1.y; CCb[6]  = sqi + o1.z; CCb[7]  = sqi + o1.w;
        CCb[8] = sqi + o2.x; CCb[9] = sqi + o2.y; CCb[10] = sqi + o2.z; CCb[11] = sqi + o2.w;
        CCb[12] = sqi + o3.x; CCb[13] = sqi + o3.y; CCb[14] = sqi + o3.z; CCb[15] = sqi + o3.w;
        #pragma unroll
        for (int s = 0; s < NS; ++s) {
            CCb = __builtin_amdgcn_mfma_f32_32x32x16_bf16(fB[s], bhi[s], CCb, 0, 0, 0);
            CCb = __builtin_amdgcn_mfma_f32_32x32x16_bf16(fB[s], blo[s], CCb, 0, 0, 0);
            CCb = __builtin_amdgcn_mfma_f32_32x32x16_bf16(lo[s], bhi[s], CCb, 0, 0, 0);
        }
    }
    PROCESS_SEL(CCb, jbase + (NT - 1) * 32);

    // merge the two h-half lists (partner lane = lane ^ 32), keep lowest 20
    {
        bool done = false;
        #pragma unroll
        for (int k = 0; k < KNN; ++k) {
            unsigned c = __shfl_xor(top[k], 32);
            if (!done) done = __all(c >= top[KNN - 1]);
            if (!done) NET(c);
        }
    }

    if (h == 0) {
        unsigned* o = part + ((size_t)bi * NLISTS + blockIdx.y) * KNN;
        #pragma unroll
        for (int k = 0; k < KNN; ++k) o[k] = top[k];
    }

    // ---- featAB tail: one row per wave (grid covers all 8192 exactly once) ----
    {
        const int n = blockIdx.x * 128 + blockIdx.y * 4 + wave;
        float a = 0.f, bb = 0.f;
        const float* xp = Xf + (size_t)n * stride;
        #pragma unroll
        for (int f = 0; f < D; ++f) {
            float xf = xp[f];
            a  = fmaf(xf, W[(size_t)f * 64 + lane], a);
            bb = fmaf(xf, W[(size_t)(D + f) * 64 + lane], bb);
        }
        A[(size_t)n * 64 + lane] = a;
        B[(size_t)n * 64 + lane] = bb;
    }
}

// ---------------- fused knnB (in-register butterfly) + edge aggregation ----------------
// One row per wave. Both 32-lane halves mirror the butterfly merge of the row's
// 32 sorted lists (keeps __all coherent); the 20 neighbor indices are then
// broadcast from lane 0 and used directly for the max-aggregation — no idx
// round-trip through memory, no separate knnB launch.
template<bool PACKS>
__global__ __launch_bounds__(256)
void edgeB_kernel(const unsigned int* __restrict__ part,
                  const float* __restrict__ A, const float* __restrict__ B,
                  const float* __restrict__ bias,
                  float* __restrict__ out, int colofs,
                  unsigned short* __restrict__ catHi, unsigned short* __restrict__ catLo,
                  float* __restrict__ sqo,
                  unsigned short* __restrict__ Xhi, unsigned short* __restrict__ Xlo,
                  unsigned short* __restrict__ Yhi, unsigned short* __restrict__ Ylo) {
    const int wave = threadIdx.x >> 6, lane = threadIdx.x & 63;
    const int n = blockIdx.x * 4 + wave;
    const int l = lane & 31;

    // load list l of row n (both halves load the same lists — mirrored merge)
    unsigned top[KNN];
    const unsigned* p = part + ((size_t)n * NLISTS + l) * KNN;
    #pragma unroll
    for (int k = 0; k < KNN; k += 4) {
        uint4 v = *(const uint4*)(p + k);
        top[k] = v.x; top[k + 1] = v.y; top[k + 2] = v.z; top[k + 3] = v.w;
    }

    #pragma unroll
    for (int mi = 0; mi < 5; ++mi) {
        const int m = 1 << mi;
        bool done = false;
        #pragma unroll
        for (int k = 0; k < KNN; ++k) {
            unsigned c = __shfl_xor(top[k], m);
            if (!done) done = __all(c >= top[KNN - 1]);
            if (!done) {
                #pragma unroll
                for (int q = KNN - 1; q >= 1; --q)
                    top[q] = umed3(c, top[q - 1], top[q]);
                top[0] = min(top[0], c);
            }
        }
    }

    // edge aggregation using broadcast indices
    const float base = A[(size_t)n * 64 + lane] - B[(size_t)n * 64 + lane] + bias[lane];
    float m = -INFINITY;
    #pragma unroll 4
    for (int k = 0; k < KNN; ++k) {
        int j = __shfl((int)(top[k] & 0x1FFFu), 0);
        m = fmaxf(m, base + B[(size_t)j * 64 + lane]);
    }
    m = fmaxf(m, 0.f);
    if (PACKS) out[(size_t)n * 192 + colofs + lane] = m;   // fp32 cat read by next conv's featAB

    unsigned short chi, clo;
    tsplit(m, chi, clo);
    catHi[(size_t)n * 192 + colofs + lane] = chi;
    catLo[(size_t)n * 192 + colofs + lane] = clo;

    if constexpr (PACKS) {
        float s = m * m;
        #pragma unroll
        for (int off = 32; off; off >>= 1) s += __shfl_xor(s, off);
        if (lane == 0) sqo[n] = s;

        unsigned short hi = f2bf(m);
        float hif = __uint_as_float((unsigned)hi << 16);
        unsigned short lo = f2bf(m - hif);
        float y = -2.f * m;
        unsigned short yhi = f2bf(y);
        float yhif = __uint_as_float((unsigned)yhi << 16);
        unsigned short ylo = f2bf(y - yhif);
        Xhi[(size_t)n * 64 + lane] = hi;
        Xlo[(size_t)n * 64 + lane] = lo;
        Yhi[(size_t)n * 64 + lane] = yhi;
        Ylo[(size_t)n * 64 + lane] = ylo;
    }
}

// ---------------- MFMA GEMM + bias + relu, pre-split operands ----------------
template<int K, int N, int CTW, bool SPLIT_OUT>
__global__ __launch_bounds__(256, 3)
void gemm_mfma(const unsigned short* __restrict__ Ahi, const unsigned short* __restrict__ Alo,
               const unsigned short* __restrict__ Whi, const unsigned short* __restrict__ Wlo,
               const float* __restrict__ bias, float* __restrict__ C,
               unsigned short* __restrict__ Chi, unsigned short* __restrict__ Clo) {
    const int wave = threadIdx.x >> 6, lane = threadIdx.x & 63;
    const int col = lane & 31, h = lane >> 5;
    const int r0 = blockIdx.x * 32;
    const int nb = blockIdx.y * (CTW * 128) + wave * (CTW * 32);
    const size_t abase = (size_t)(r0 + col) * K + h * 8;

    f32x16 acc[CTW];
    #pragma unroll
    for (int c = 0; c < CTW; ++c)
        #pragma unroll
        for (int r = 0; r < 16; ++r) acc[c][r] = 0.f;

    #pragma unroll 4
    for (int s = 0; s < K / 16; ++s) {
        bf16x8 ahi = *(const bf16x8*)&Ahi[abase + s * 16];
        bf16x8 alo = *(const bf16x8*)&Alo[abase + s * 16];
        #pragma unroll
        for (int c = 0; c < CTW; ++c) {
            const size_t wb = (size_t)(nb + c * 32 + col) * K + s * 16 + h * 8;
            bf16x8 bhi = *(const bf16x8*)&Whi[wb];
            bf16x8 blo = *(const bf16x8*)&Wlo[wb];
            acc[c] = __builtin_amdgcn_mfma_f32_32x32x16_bf16(ahi, bhi, acc[c], 0, 0, 0);
            acc[c] = __builtin_amdgcn_mfma_f32_32x32x16_bf16(alo, bhi, acc[c], 0, 0, 0);
            acc[c] = __builtin_amdgcn_mfma_f32_32x32x16_bf16(ahi, blo, acc[c], 0, 0, 0);
        }
    }

    #pragma unroll
    for (int c = 0; c < CTW; ++c) {
        const int n = nb + c * 32 + col;
        const float b = bias[n];
        #pragma unroll
        for (int q = 0; q < 4; ++q)
            #pragma unroll
            for (int t = 0; t < 4; ++t) {
                const int rl = 4 * h + 8 * q + t;
                float v = fmaxf(acc[c][q * 4 + t] + b, 0.f);
                if constexpr (SPLIT_OUT) {
                    unsigned short vh, vl;
                    tsplit(v, vh, vl);
                    Chi[(size_t)(r0 + rl) * N + n] = vh;
                    Clo[(size_t)(r0 + rl) * N + n] = vl;
                } else {
                    C[(size_t)(r0 + rl) * N + n] = v;
                }
            }
    }
}

// ---------------- final FC (128->50) + log_softmax ----------------
__global__ __launch_bounds__(256)
void final_kernel(const float* __restrict__ H, const float* __restrict__ Wo,
                  const float* __restrict__ bo, float* __restrict__ out) {
    const int wave = threadIdx.x >> 6, lane = threadIdx.x & 63;
    const int n = blockIdx.x * 4 + wave;
    float v = -INFINITY;
    if (lane < 50) {
        float a = bo[lane];
        const float* h = H + (size_t)n * 128;
        #pragma unroll 4
        for (int f = 0; f < 128; ++f) a = fmaf(h[f], Wo[f * 50 + lane], a);
        v = a;
    }
    float mx = v;
    #pragma unroll
    for (int off = 32; off; off >>= 1) mx = fmaxf(mx, __shfl_xor(mx, off));
    float e = (lane < 50) ? expf(v - mx) : 0.f;
    float s = e;
    #pragma unroll
    for (int off = 32; off; off >>= 1) s += __shfl_xor(s, off);
    if (lane < 50) out[(size_t)n * 50 + lane] = v - mx - logf(s);
}

extern "C" void kernel_launch(void* const* d_in, const int* in_sizes, int n_in,
                              void* d_out, int out_size, void* d_ws, size_t ws_size,
                              hipStream_t stream) {
    const float* x   = (const float*)d_in[0];
    const float* W1  = (const float*)d_in[1];
    const float* b1  = (const float*)d_in[2];
    const float* W2  = (const float*)d_in[3];
    const float* b2  = (const float*)d_in[4];
    const float* W3  = (const float*)d_in[5];
    const float* b3  = (const float*)d_in[6];
    const float* Wl  = (const float*)d_in[7];
    const float* bl  = (const float*)d_in[8];
    const float* Wm1 = (const float*)d_in[9];
    const float* bm1 = (const float*)d_in[10];
    const float* Wm2 = (const float*)d_in[11];
    const float* bm2 = (const float*)d_in[12];
    const float* Wo  = (const float*)d_in[13];
    const float* bo  = (const float*)d_in[14];

    float* ws   = (float*)d_ws;
    float* sq   = ws + OFF_SQ;
    float* Abuf = ws + OFF_A;
    float* Bbuf = ws + OFF_B;
    float* cat  = ws + OFF_CAT;
    unsigned int* part = (unsigned int*)(ws + OFF_PART);
    unsigned short* Phi = (unsigned short*)(ws + OFF_PACK);
    unsigned short* Plo = (unsigned short*)(ws + OFF_PACK + PACK_ELEMS);
    unsigned short* Qhi = (unsigned short*)(ws + OFF_PACK + 2 * PACK_ELEMS);
    unsigned short* Qlo = (unsigned short*)(ws + OFF_PACK + 3 * PACK_ELEMS);
    unsigned short* h1hi = (unsigned short*)(ws + OFF_H1);
    unsigned short* h1lo = (unsigned short*)(ws + OFF_H1 + 4194304);
    unsigned short* catHi = (unsigned short*)(ws + OFF_H2);
    unsigned short* catLo = (unsigned short*)(ws + OFF_H2 + 786432);
    unsigned short* h2hi = (unsigned short*)(ws + OFF_H2);          // written after catXX dead
    unsigned short* h2lo = (unsigned short*)(ws + OFF_H2 + 1048576);
    float* h3   = ws + OFF_H3;
    unsigned short* WlT_hi  = (unsigned short*)(ws + OFF_WT);
    unsigned short* WlT_lo  = (unsigned short*)(ws + OFF_WT + 98304);
    unsigned short* Wm1T_hi = (unsigned short*)(ws + OFF_WT + 196608);
    unsigned short* Wm1T_lo = (unsigned short*)(ws + OFF_WT + 327680);
    unsigned short* Wm2T_hi = (unsigned short*)(ws + OFF_WT + 458752);
    unsigned short* Wm2T_lo = (unsigned short*)(ws + OFF_WT + 475136);
    float* out  = (float*)d_out;

    dim3 b256(256);
    dim3 gknn(64, 32);

    // conv1 (kNN on raw 3-D points, K padded to 16; featAB<3> fused into knnA)
    setup_kernel<<<288, b256, 0, stream>>>(x, sq, Phi, Plo, Qhi, Qlo);
    knnA_mfma<16, 3><<<gknn, b256, 0, stream>>>(Qhi, Qlo, Phi, Plo, sq, part,
                                                x, 3, W1, Abuf, Bbuf);
    edgeB_kernel<true><<<2048, b256, 0, stream>>>(part, Abuf, Bbuf, b1, cat, 0,
                                                  catHi, catLo, sq, Phi, Plo, Qhi, Qlo);

    // conv2
    knnA_mfma<64, 64><<<gknn, b256, 0, stream>>>(Qhi, Qlo, Phi, Plo, sq, part,
                                                 cat, 192, W2, Abuf, Bbuf);
    edgeB_kernel<true><<<2048, b256, 0, stream>>>(part, Abuf, Bbuf, b2, cat, 64,
                                                  catHi, catLo, sq, Phi, Plo, Qhi, Qlo);

    // conv3
    knnA_mfma<64, 64><<<gknn, b256, 0, stream>>>(Qhi, Qlo, Phi, Plo, sq, part,
                                                 cat + 64, 192, W3, Abuf, Bbuf);
    edgeB_kernel<false><<<2048, b256, 0, stream>>>(part, Abuf, Bbuf, b3, cat, 128,
                                                   catHi, catLo, nullptr,
                                                   nullptr, nullptr, nullptr, nullptr);

    // MLP head — W prepack (A-region free), then pre-split MFMA GEMMs
    wprep_kernel<<<1920, b256, 0, stream>>>(Wl, Wm1, Wm2, WlT_hi, WlT_lo,
                                            Wm1T_hi, Wm1T_lo, Wm2T_hi, Wm2T_lo);

    dim3 g1(256, 4);
    gemm_mfma<192, 1024, 2, true><<<g1, b256, 0, stream>>>(catHi, catLo, WlT_hi, WlT_lo,
                                                           bl, nullptr, h1hi, h1lo);
    dim3 g2(256, 2);
    gemm_mfma<1024, 256, 1, true><<<g2, b256, 0, stream>>>(h1hi, h1lo, Wm1T_hi, Wm1T_lo,
                                                           bm1, nullptr, h2hi, h2lo);
    dim3 g3(256, 1);
    gemm_mfma<256, 128, 1, false><<<g3, b256, 0, stream>>>(h2hi, h2lo, Wm2T_hi, Wm2T_lo,
                                                           bm2, h3, nullptr, nullptr);
    final_kernel<<<2048, b256, 0, stream>>>(h3, Wo, bo, out);
}

// Round 13
// 470.950 us; speedup vs baseline: 1.1101x; 1.1101x over previous
//
#include <hip/hip_runtime.h>
#include <math.h>

#define NPTS 8192
#define KNN 20
#define NLISTS 32     // partial lists per row = blockIdx.y count of knnA

// workspace layout in floats
#define OFF_SQ   0          // 8192
#define OFF_IDX  8192       // 8192*20 ints
#define OFF_A    172032     // 8192*64 (featAB A; region reused for W packs in MLP phase)
#define OFF_B    696320     // 8192*64
#define OFF_CAT  1220608    // 8192*192 fp32
#define OFF_H1   2793472    // region: kNN part+packs during convs; h1 split-bf16 in MLP phase
#define OFF_H2   11182080   // region: cat split-bf16 during convs/gemm1; h2 split-bf16 after
#define OFF_H3   13279232   // 8192*128 fp32
#define OFF_PART OFF_H1                       // 8192*32*20 u32 = 5242880 slots
#define OFF_PACK (OFF_H1 + 5242880)           // 4 arrays x 262144 float-slots (bf16 [8192][64])
#define PACK_ELEMS 262144
#define OFF_WT   OFF_A                        // W packs (491520 float-slots), after conv3

typedef __attribute__((ext_vector_type(8))) short bf16x8;
typedef __attribute__((ext_vector_type(16))) float f32x16;

__device__ inline unsigned umed3(unsigned a, unsigned b, unsigned c) {
    unsigned d;
    asm("v_med3_u32 %0, %1, %2, %3" : "=v"(d) : "v"(a), "v"(b), "v"(c));
    return d;
}

__device__ inline unsigned short f2bf(float f) {   // round-to-nearest-even bf16
    unsigned u = __float_as_uint(f);
    u += 0x7FFFu + ((u >> 16) & 1u);
    return (unsigned short)(u >> 16);
}

__device__ inline void tsplit(float x, unsigned short& hi, unsigned short& lo) {
    unsigned u = __float_as_uint(x);
    hi = (unsigned short)(u >> 16);
    float d = x - __uint_as_float(u & 0xFFFF0000u);
    lo = (unsigned short)(__float_as_uint(d) >> 16);
}

// ---------------- setup: conv1 prepack (blocks 0..255) + sqnorm (blocks 256..287) ----
__global__ __launch_bounds__(256)
void setup_kernel(const float* __restrict__ x, float* __restrict__ sq,
                  unsigned short* __restrict__ Xhi, unsigned short* __restrict__ Xlo,
                  unsigned short* __restrict__ Yhi, unsigned short* __restrict__ Ylo) {
    const int b = blockIdx.x;
    if (b < 256) {
        int t = (b * 256 + threadIdx.x) * 2;      // over NPTS*16
        int n = t >> 4, k = t & 15;
        float xv[2];
        xv[0] = (k < 3) ? x[(size_t)n * 3 + k] : 0.f;
        xv[1] = (k + 1 < 3) ? x[(size_t)n * 3 + k + 1] : 0.f;
        ushort2 hx, lx, hy, ly;
        unsigned short* hxp = (unsigned short*)&hx;
        unsigned short* lxp = (unsigned short*)&lx;
        unsigned short* hyp = (unsigned short*)&hy;
        unsigned short* lyp = (unsigned short*)&ly;
        #pragma unroll
        for (int e = 0; e < 2; ++e) {
            float xx = xv[e];
            unsigned short hi = f2bf(xx);
            float hif = __uint_as_float((unsigned)hi << 16);
            unsigned short lo = f2bf(xx - hif);
            float y = -2.f * xx;
            unsigned short yhi = f2bf(y);
            float yhif = __uint_as_float((unsigned)yhi << 16);
            unsigned short ylo = f2bf(y - yhif);
            hxp[e] = hi; lxp[e] = lo; hyp[e] = yhi; lyp[e] = ylo;
        }
        *(ushort2*)&Xhi[t] = hx;
        *(ushort2*)&Xlo[t] = lx;
        *(ushort2*)&Yhi[t] = hy;
        *(ushort2*)&Ylo[t] = ly;
    } else {
        int n = (b - 256) * 256 + threadIdx.x;
        float a = x[(size_t)n * 3], bb = x[(size_t)n * 3 + 1], c = x[(size_t)n * 3 + 2];
        sq[n] = fmaf(a, a, fmaf(bb, bb, c * c));
    }
}

// ---------------- fused W prepack: W[K][N] fp32 -> [N][K] split-bf16, 3 matrices ----
__global__ __launch_bounds__(256)
void wprep_kernel(const float* __restrict__ Wl, const float* __restrict__ Wm1,
                  const float* __restrict__ Wm2,
                  unsigned short* __restrict__ WlT_hi, unsigned short* __restrict__ WlT_lo,
                  unsigned short* __restrict__ Wm1T_hi, unsigned short* __restrict__ Wm1T_lo,
                  unsigned short* __restrict__ Wm2T_hi, unsigned short* __restrict__ Wm2T_lo) {
    const int b = blockIdx.x;
    const float* W; unsigned short *Thi, *Tlo; int t, K, nmask, nbits;
    if (b < 768)       { W = Wl;  Thi = WlT_hi;  Tlo = WlT_lo;  t = b * 256 + threadIdx.x;          K = 192;  nbits = 10; }
    else if (b < 1792) { W = Wm1; Thi = Wm1T_hi; Tlo = Wm1T_lo; t = (b - 768) * 256 + threadIdx.x;  K = 1024; nbits = 8; }
    else               { W = Wm2; Thi = Wm2T_hi; Tlo = Wm2T_lo; t = (b - 1792) * 256 + threadIdx.x; K = 256;  nbits = 7; }
    nmask = (1 << nbits) - 1;
    int k = t >> nbits, n = t & nmask;
    float xx = W[t];
    unsigned short hi = f2bf(xx);
    float hif = __uint_as_float((unsigned)hi << 16);
    unsigned short lo = f2bf(xx - hif);
    Thi[(size_t)n * K + k] = hi;
    Tlo[(size_t)n * K + k] = lo;
}

// sorted-insert network on a NAMED key (rule #20: no address-taking)
#define NET(key)                                                               \
    do {                                                                       \
        _Pragma("unroll")                                                      \
        for (int p = KNN - 1; p >= 1; --p)                                     \
            top[p] = umed3(key, top[p - 1], top[p]);                           \
        top[0] = min(top[0], key);                                             \
    } while (0)

// candidate processing WITHOUT self-exclusion (j != bi guaranteed for this tile)
#define PROCESS_NX(Cv, j0base)                                                 \
    do {                                                                       \
        _Pragma("unroll")                                                      \
        for (int q = 0; q < 4; ++q) {                                          \
            _Pragma("unroll")                                                  \
            for (int t = 0; t < 4; ++t) {                                      \
                const int j = (j0base) + h * 4 + q * 8 + t;                    \
                float dd = fmaxf((Cv)[q * 4 + t], 0.f);                        \
                unsigned key = (__float_as_uint(dd) & 0xFFFFE000u) | (unsigned)j; \
                NET(key);                                                      \
            }                                                                  \
        }                                                                      \
    } while (0)

// candidate processing WITH self-exclusion (tile may contain j == bi)
#define PROCESS_EX(Cv, j0base)                                                 \
    do {                                                                       \
        _Pragma("unroll")                                                      \
        for (int q = 0; q < 4; ++q) {                                          \
            _Pragma("unroll")                                                  \
            for (int t = 0; t < 4; ++t) {                                      \
                const int j = (j0base) + h * 4 + q * 8 + t;                    \
                float dd = fmaxf((Cv)[q * 4 + t], 0.f);                        \
                unsigned key = (__float_as_uint(dd) & 0xFFFFE000u) | (unsigned)j; \
                if (j == bi) key = 0xFFFFFFFFu;                                \
                NET(key);                                                      \
            }                                                                  \
        }                                                                      \
    } while (0)

// wave-uniform selector: only the tile whose base == wave's i-block can self-hit
#define PROCESS_SEL(Cv, j0base)                                                \
    do {                                                                       \
        if ((j0base) == myTile) PROCESS_EX(Cv, j0base);                        \
        else                    PROCESS_NX(Cv, j0base);                        \
    } while (0)

// ---------------- kNN phase A via MFMA, software-pipelined (r10 structure) ----------------
template<int KP>
__global__ __launch_bounds__(256, 2)
void knnA_mfma(const unsigned short* __restrict__ Yhi, const unsigned short* __restrict__ Ylo,
               const unsigned short* __restrict__ Xhi, const unsigned short* __restrict__ Xlo,
               const float* __restrict__ sq, unsigned int* __restrict__ part) {
    constexpr int NS = KP / 16;
    constexpr int NT = 8;
    const int wave = threadIdx.x >> 6, lane = threadIdx.x & 63;
    const int col = lane & 31;
    const int h   = lane >> 5;
    const int bi  = (blockIdx.x * 4 + wave) * 32 + col;
    const int myTile = bi - col;          // wave-uniform
    const int jbase = blockIdx.y * 256;

    bf16x8 bhi[NS], blo[NS];
    #pragma unroll
    for (int s = 0; s < NS; ++s) {
        bhi[s] = *(const bf16x8*)&Xhi[(size_t)bi * KP + s * 16 + h * 8];
        blo[s] = *(const bf16x8*)&Xlo[(size_t)bi * KP + s * 16 + h * 8];
    }
    const float sqi = sq[bi];

    unsigned top[KNN];
    #pragma unroll
    for (int k = 0; k < KNN; ++k) top[k] = 0xFFFFFFFFu;

    bf16x8 fA[NS], fB[NS], lo[NS];
    f32x16 CCa, CCb;

    {
        const size_t a0 = (size_t)(jbase + col) * KP + h * 8;
        #pragma unroll
        for (int s = 0; s < NS; ++s)
            fA[s] = *(const bf16x8*)&Yhi[a0 + s * 16];
    }

    #pragma unroll 1
    for (int jt2 = 0; jt2 < NT; jt2 += 2) {
        const int j0 = jbase + jt2 * 32;
        const int aj = j0 + col;

        #pragma unroll
        for (int s = 0; s < NS; ++s)
            fB[s] = *(const bf16x8*)&Yhi[(size_t)(aj + 32) * KP + s * 16 + h * 8];
        #pragma unroll
        for (int s = 0; s < NS; ++s)
            lo[s] = *(const bf16x8*)&Ylo[(size_t)aj * KP + s * 16 + h * 8];
        float4 e0 = *(const float4*)&sq[j0 + h * 4];
        float4 e1 = *(const float4*)&sq[j0 + h * 4 + 8];
        float4 e2 = *(const float4*)&sq[j0 + h * 4 + 16];
        float4 e3 = *(const float4*)&sq[j0 + h * 4 + 24];

        if (jt2 > 0) PROCESS_SEL(CCb, j0 - 32);

        CCa[0] = sqi + e0.x; CCa[1] = sqi + e0.y; CCa[2]  = sqi + e0.z; CCa[3]  = sqi + e0.w;
        CCa[4] = sqi + e1.x; CCa[5] = sqi + e1.y; CCa[6]  = sqi + e1.z; CCa[7]  = sqi + e1.w;
        CCa[8] = sqi + e2.x; CCa[9] = sqi + e2.y; CCa[10] = sqi + e2.z; CCa[11] = sqi + e2.w;
        CCa[12] = sqi + e3.x; CCa[13] = sqi + e3.y; CCa[14] = sqi + e3.z; CCa[15] = sqi + e3.w;
        #pragma unroll
        for (int s = 0; s < NS; ++s) {
            CCa = __builtin_amdgcn_mfma_f32_32x32x16_bf16(fA[s], bhi[s], CCa, 0, 0, 0);
            CCa = __builtin_amdgcn_mfma_f32_32x32x16_bf16(fA[s], blo[s], CCa, 0, 0, 0);
            CCa = __builtin_amdgcn_mfma_f32_32x32x16_bf16(lo[s], bhi[s], CCa, 0, 0, 0);
        }

        if (jt2 + 2 < NT) {
            #pragma unroll
            for (int s = 0; s < NS; ++s)
                fA[s] = *(const bf16x8*)&Yhi[(size_t)(aj + 64) * KP + s * 16 + h * 8];
        }
        #pragma unroll
        for (int s = 0; s < NS; ++s)
            lo[s] = *(const bf16x8*)&Ylo[(size_t)(aj + 32) * KP + s * 16 + h * 8];
        float4 o0 = *(const float4*)&sq[j0 + 32 + h * 4];
        float4 o1 = *(const float4*)&sq[j0 + 32 + h * 4 + 8];
        float4 o2 = *(const float4*)&sq[j0 + 32 + h * 4 + 16];
        float4 o3 = *(const float4*)&sq[j0 + 32 + h * 4 + 24];

        PROCESS_SEL(CCa, j0);

        CCb[0] = sqi + o0.x; CCb[1] = sqi + o0.y; CCb[2]  = sqi + o0.z; CCb[3]  = sqi + o0.w;
        CCb[4] = sqi + o1.x; CCb[5] = sqi + o1.y; CCb[6]  = sqi + o1.z; CCb[7]  = sqi + o1.w;
        CCb[8] = sqi + o2.x; CCb[9] = sqi + o2.y; CCb[10] = sqi + o2.z; CCb[11] = sqi + o2.w;
        CCb[12] = sqi + o3.x; CCb[13] = sqi + o3.y; CCb[14] = sqi + o3.z; CCb[15] = sqi + o3.w;
        #pragma unroll
        for (int s = 0; s < NS; ++s) {
            CCb = __builtin_amdgcn_mfma_f32_32x32x16_bf16(fB[s], bhi[s], CCb, 0, 0, 0);
            CCb = __builtin_amdgcn_mfma_f32_32x32x16_bf16(fB[s], blo[s], CCb, 0, 0, 0);
            CCb = __builtin_amdgcn_mfma_f32_32x32x16_bf16(lo[s], bhi[s], CCb, 0, 0, 0);
        }
    }
    PROCESS_SEL(CCb, jbase + (NT - 1) * 32);

    // merge the two h-half lists (partner lane = lane ^ 32), keep lowest 20
    {
        bool done = false;
        #pragma unroll
        for (int k = 0; k < KNN; ++k) {
            unsigned c = __shfl_xor(top[k], 32);
            if (!done) done = __all(c >= top[KNN - 1]);
            if (!done) NET(c);
        }
    }

    if (h == 0) {
        unsigned* o = part + ((size_t)bi * NLISTS + blockIdx.y) * KNN;
        #pragma unroll
        for (int k = 0; k < KNN; ++k) o[k] = top[k];
    }
}

// ---------------- fused kNN phase B (blocks 0..1023) + featAB (blocks 1024..3071) ----
template<int D>
__global__ __launch_bounds__(256)
void knnBfeat_kernel(const unsigned int* __restrict__ part, int* __restrict__ idx_out,
                     const float* __restrict__ X, int stride, const float* __restrict__ W,
                     float* __restrict__ A, float* __restrict__ B) {
    const int wave = threadIdx.x >> 6, lane = threadIdx.x & 63;
    if (blockIdx.x < 1024) {
        const int half = lane >> 5;
        const int l = lane & 31;
        const int row = (blockIdx.x * 4 + wave) * 2 + half;

        unsigned top[KNN];
        const unsigned* p = part + ((size_t)row * NLISTS + l) * KNN;
        #pragma unroll
        for (int k = 0; k < KNN; k += 4) {
            uint4 v = *(const uint4*)(p + k);
            top[k] = v.x; top[k + 1] = v.y; top[k + 2] = v.z; top[k + 3] = v.w;
        }

        #pragma unroll
        for (int mi = 0; mi < 5; ++mi) {
            const int m = 1 << mi;
            bool done = false;
            #pragma unroll
            for (int k = 0; k < KNN; ++k) {
                unsigned c = __shfl_xor(top[k], m);
                if (!done) done = __all(c >= top[KNN - 1]);
                if (!done) {
                    #pragma unroll
                    for (int q = KNN - 1; q >= 1; --q)
                        top[q] = umed3(c, top[q - 1], top[q]);
                    top[0] = min(top[0], c);
                }
            }
        }

        if (l == 0) {
            #pragma unroll
            for (int k = 0; k < KNN; ++k)
                idx_out[(size_t)row * KNN + k] = (int)(top[k] & 0x1FFFu);
        }
    } else {
        const int n = (blockIdx.x - 1024) * 4 + wave;
        float a = 0.f, b = 0.f;
        const float* xp = X + (size_t)n * stride;
        #pragma unroll
        for (int f = 0; f < D; ++f) {
            float xf = xp[f];
            a = fmaf(xf, W[(size_t)f * 64 + lane], a);
            b = fmaf(xf, W[(size_t)(D + f) * 64 + lane], b);
        }
        A[(size_t)n * 64 + lane] = a;
        B[(size_t)n * 64 + lane] = b;
    }
}

// ---------------- fused edge aggregation (+cat split stripe) [+sqnorm+knn packs] ----
template<bool PACKS>
__global__ __launch_bounds__(256)
void edge_fuse_kernel(const float* __restrict__ A, const float* __restrict__ B,
                      const int* __restrict__ idx, const float* __restrict__ bias,
                      float* __restrict__ out, int colofs,
                      unsigned short* __restrict__ catHi, unsigned short* __restrict__ catLo,
                      float* __restrict__ sqo,
                      unsigned short* __restrict__ Xhi, unsigned short* __restrict__ Xlo,
                      unsigned short* __restrict__ Yhi, unsigned short* __restrict__ Ylo) {
    const int wave = threadIdx.x >> 6, lane = threadIdx.x & 63;
    const int n = blockIdx.x * 4 + wave;
    const float base = A[(size_t)n * 64 + lane] - B[(size_t)n * 64 + lane] + bias[lane];
    float m = -INFINITY;
    #pragma unroll 4
    for (int k = 0; k < KNN; ++k) {
        int j = idx[(size_t)n * KNN + k];
        m = fmaxf(m, base + B[(size_t)j * 64 + lane]);
    }
    m = fmaxf(m, 0.f);
    if constexpr (PACKS) out[(size_t)n * 192 + colofs + lane] = m;  // fp32 cat only read by next conv

    unsigned short chi, clo;
    tsplit(m, chi, clo);
    catHi[(size_t)n * 192 + colofs + lane] = chi;
    catLo[(size_t)n * 192 + colofs + lane] = clo;

    if constexpr (PACKS) {
        float s = m * m;
        #pragma unroll
        for (int off = 32; off; off >>= 1) s += __shfl_xor(s, off);
        if (lane == 0) sqo[n] = s;

        unsigned short hi = f2bf(m);
        float hif = __uint_as_float((unsigned)hi << 16);
        unsigned short lo = f2bf(m - hif);
        float y = -2.f * m;
        unsigned short yhi = f2bf(y);
        float yhif = __uint_as_float((unsigned)yhi << 16);
        unsigned short ylo = f2bf(y - yhif);
        Xhi[(size_t)n * 64 + lane] = hi;
        Xlo[(size_t)n * 64 + lane] = lo;
        Yhi[(size_t)n * 64 + lane] = yhi;
        Ylo[(size_t)n * 64 + lane] = ylo;
    }
}

// ---------------- MFMA GEMM + bias + relu, pre-split operands ----------------
template<int K, int N, int CTW, bool SPLIT_OUT>
__global__ __launch_bounds__(256, 3)
void gemm_mfma(const unsigned short* __restrict__ Ahi, const unsigned short* __restrict__ Alo,
               const unsigned short* __restrict__ Whi, const unsigned short* __restrict__ Wlo,
               const float* __restrict__ bias, float* __restrict__ C,
               unsigned short* __restrict__ Chi, unsigned short* __restrict__ Clo) {
    const int wave = threadIdx.x >> 6, lane = threadIdx.x & 63;
    const int col = lane & 31, h = lane >> 5;
    const int r0 = blockIdx.x * 32;
    const int nb = blockIdx.y * (CTW * 128) + wave * (CTW * 32);
    const size_t abase = (size_t)(r0 + col) * K + h * 8;

    f32x16 acc[CTW];
    #pragma unroll
    for (int c = 0; c < CTW; ++c)
        #pragma unroll
        for (int r = 0; r < 16; ++r) acc[c][r] = 0.f;

    #pragma unroll 4
    for (int s = 0; s < K / 16; ++s) {
        bf16x8 ahi = *(const bf16x8*)&Ahi[abase + s * 16];
        bf16x8 alo = *(const bf16x8*)&Alo[abase + s * 16];
        #pragma unroll
        for (int c = 0; c < CTW; ++c) {
            const size_t wb = (size_t)(nb + c * 32 + col) * K + s * 16 + h * 8;
            bf16x8 bhi = *(const bf16x8*)&Whi[wb];
            bf16x8 blo = *(const bf16x8*)&Wlo[wb];
            acc[c] = __builtin_amdgcn_mfma_f32_32x32x16_bf16(ahi, bhi, acc[c], 0, 0, 0);
            acc[c] = __builtin_amdgcn_mfma_f32_32x32x16_bf16(alo, bhi, acc[c], 0, 0, 0);
            acc[c] = __builtin_amdgcn_mfma_f32_32x32x16_bf16(ahi, blo, acc[c], 0, 0, 0);
        }
    }

    #pragma unroll
    for (int c = 0; c < CTW; ++c) {
        const int n = nb + c * 32 + col;
        const float b = bias[n];
        #pragma unroll
        for (int q = 0; q < 4; ++q)
            #pragma unroll
            for (int t = 0; t < 4; ++t) {
                const int rl = 4 * h + 8 * q + t;
                float v = fmaxf(acc[c][q * 4 + t] + b, 0.f);
                if constexpr (SPLIT_OUT) {
                    unsigned short vh, vl;
                    tsplit(v, vh, vl);
                    Chi[(size_t)(r0 + rl) * N + n] = vh;
                    Clo[(size_t)(r0 + rl) * N + n] = vl;
                } else {
                    C[(size_t)(r0 + rl) * N + n] = v;
                }
            }
    }
}

// ---------------- final FC (128->50) + log_softmax ----------------
__global__ __launch_bounds__(256)
void final_kernel(const float* __restrict__ H, const float* __restrict__ Wo,
                  const float* __restrict__ bo, float* __restrict__ out) {
    const int wave = threadIdx.x >> 6, lane = threadIdx.x & 63;
    const int n = blockIdx.x * 4 + wave;
    float v = -INFINITY;
    if (lane < 50) {
        float a = bo[lane];
        const float* h = H + (size_t)n * 128;
        #pragma unroll 4
        for (int f = 0; f < 128; ++f) a = fmaf(h[f], Wo[f * 50 + lane], a);
        v = a;
    }
    float mx = v;
    #pragma unroll
    for (int off = 32; off; off >>= 1) mx = fmaxf(mx, __shfl_xor(mx, off));
    float e = (lane < 50) ? expf(v - mx) : 0.f;
    float s = e;
    #pragma unroll
    for (int off = 32; off; off >>= 1) s += __shfl_xor(s, off);
    if (lane < 50) out[(size_t)n * 50 + lane] = v - mx - logf(s);
}

extern "C" void kernel_launch(void* const* d_in, const int* in_sizes, int n_in,
                              void* d_out, int out_size, void* d_ws, size_t ws_size,
                              hipStream_t stream) {
    const float* x   = (const float*)d_in[0];
    const float* W1  = (const float*)d_in[1];
    const float* b1  = (const float*)d_in[2];
    const float* W2  = (const float*)d_in[3];
    const float* b2  = (const float*)d_in[4];
    const float* W3  = (const float*)d_in[5];
    const float* b3  = (const float*)d_in[6];
    const float* Wl  = (const float*)d_in[7];
    const float* bl  = (const float*)d_in[8];
    const float* Wm1 = (const float*)d_in[9];
    const float* bm1 = (const float*)d_in[10];
    const float* Wm2 = (const float*)d_in[11];
    const float* bm2 = (const float*)d_in[12];
    const float* Wo  = (const float*)d_in[13];
    const float* bo  = (const float*)d_in[14];

    float* ws   = (float*)d_ws;
    float* sq   = ws + OFF_SQ;
    int*   idx  = (int*)(ws + OFF_IDX);
    float* Abuf = ws + OFF_A;
    float* Bbuf = ws + OFF_B;
    float* cat  = ws + OFF_CAT;
    unsigned int* part = (unsigned int*)(ws + OFF_PART);
    unsigned short* Phi = (unsigned short*)(ws + OFF_PACK);
    unsigned short* Plo = (unsigned short*)(ws + OFF_PACK + PACK_ELEMS);
    unsigned short* Qhi = (unsigned short*)(ws + OFF_PACK + 2 * PACK_ELEMS);
    unsigned short* Qlo = (unsigned short*)(ws + OFF_PACK + 3 * PACK_ELEMS);
    unsigned short* h1hi = (unsigned short*)(ws + OFF_H1);
    unsigned short* h1lo = (unsigned short*)(ws + OFF_H1 + 4194304);
    unsigned short* catHi = (unsigned short*)(ws + OFF_H2);
    unsigned short* catLo = (unsigned short*)(ws + OFF_H2 + 786432);
    unsigned short* h2hi = (unsigned short*)(ws + OFF_H2);          // written after catXX dead
    unsigned short* h2lo = (unsigned short*)(ws + OFF_H2 + 1048576);
    float* h3   = ws + OFF_H3;
    unsigned short* WlT_hi  = (unsigned short*)(ws + OFF_WT);
    unsigned short* WlT_lo  = (unsigned short*)(ws + OFF_WT + 98304);
    unsigned short* Wm1T_hi = (unsigned short*)(ws + OFF_WT + 196608);
    unsigned short* Wm1T_lo = (unsigned short*)(ws + OFF_WT + 327680);
    unsigned short* Wm2T_hi = (unsigned short*)(ws + OFF_WT + 458752);
    unsigned short* Wm2T_lo = (unsigned short*)(ws + OFF_WT + 475136);
    float* out  = (float*)d_out;

    dim3 b256(256);
    dim3 gknn(64, 32);

    // conv1 (kNN on raw 3-D points, K padded to 16)
    setup_kernel<<<288, b256, 0, stream>>>(x, sq, Phi, Plo, Qhi, Qlo);
    knnA_mfma<16><<<gknn, b256, 0, stream>>>(Qhi, Qlo, Phi, Plo, sq, part);
    knnBfeat_kernel<3><<<3072, b256, 0, stream>>>(part, idx, x, 3, W1, Abuf, Bbuf);
    edge_fuse_kernel<true><<<2048, b256, 0, stream>>>(Abuf, Bbuf, idx, b1, cat, 0,
                                                      catHi, catLo, sq, Phi, Plo, Qhi, Qlo);

    // conv2
    knnA_mfma<64><<<gknn, b256, 0, stream>>>(Qhi, Qlo, Phi, Plo, sq, part);
    knnBfeat_kernel<64><<<3072, b256, 0, stream>>>(part, idx, cat, 192, W2, Abuf, Bbuf);
    edge_fuse_kernel<true><<<2048, b256, 0, stream>>>(Abuf, Bbuf, idx, b2, cat, 64,
                                                      catHi, catLo, sq, Phi, Plo, Qhi, Qlo);

    // conv3
    knnA_mfma<64><<<gknn, b256, 0, stream>>>(Qhi, Qlo, Phi, Plo, sq, part);
    knnBfeat_kernel<64><<<3072, b256, 0, stream>>>(part, idx, cat + 64, 192, W3, Abuf, Bbuf);
    edge_fuse_kernel<false><<<2048, b256, 0, stream>>>(Abuf, Bbuf, idx, b3, cat, 128,
                                                       catHi, catLo, nullptr,
                                                       nullptr, nullptr, nullptr, nullptr);

    // MLP head — W prepack (A-region free), then pre-split MFMA GEMMs
    wprep_kernel<<<1920, b256, 0, stream>>>(Wl, Wm1, Wm2, WlT_hi, WlT_lo,
                                            Wm1T_hi, Wm1T_lo, Wm2T_hi, Wm2T_lo);

    dim3 g1(256, 4);
    gemm_mfma<192, 1024, 2, true><<<g1, b256, 0, stream>>>(catHi, catLo, WlT_hi, WlT_lo,
                                                           bl, nullptr, h1hi, h1lo);
    dim3 g2(256, 2);
    gemm_mfma<1024, 256, 1, true><<<g2, b256, 0, stream>>>(h1hi, h1lo, Wm1T_hi, Wm1T_lo,
                                                           bm1, nullptr, h2hi, h2lo);
    dim3 g3(256, 1);
    gemm_mfma<256, 128, 1, false><<<g3, b256, 0, stream>>>(h2hi, h2lo, Wm2T_hi, Wm2T_lo,
                                                           bm2, h3, nullptr, nullptr);
    final_kernel<<<2048, b256, 0, stream>>>(h3, Wo, bo, out);
}

// Round 14
// 440.127 us; speedup vs baseline: 1.1878x; 1.0700x over previous
//
#include <hip/hip_runtime.h>
#include <math.h>

#define NPTS 8192
#define KNN 20
#define KPART 12      // per-chunk partial-list depth (P[>12 of top-20 in one 1/32 chunk] ~ 1e-14/cell)
#define NLISTS 32     // partial lists per row = blockIdx.y count of knnA

// workspace layout in floats
#define OFF_SQ   0          // 8192
#define OFF_IDX  8192       // 8192*20 ints
#define OFF_A    172032     // 8192*64 (featAB A; region reused for W packs in MLP phase)
#define OFF_B    696320     // 8192*64
#define OFF_CAT  1220608    // 8192*192 fp32
#define OFF_H1   2793472    // region: kNN part+packs during convs; h1 split-bf16 in MLP phase
#define OFF_H2   11182080   // region: cat split-bf16 during convs/gemm1; h2 split-bf16 after
#define OFF_H3   13279232   // 8192*128 fp32
#define OFF_PART OFF_H1                       // 8192*32*12 u32 = 3145728 slots
#define OFF_PACK (OFF_H1 + 5242880)           // 4 arrays x 262144 float-slots (bf16 [8192][64])
#define PACK_ELEMS 262144
#define OFF_WT   OFF_A                        // W packs (491520 float-slots), after conv3

typedef __attribute__((ext_vector_type(8))) short bf16x8;
typedef __attribute__((ext_vector_type(16))) float f32x16;

__device__ inline unsigned umed3(unsigned a, unsigned b, unsigned c) {
    unsigned d;
    asm("v_med3_u32 %0, %1, %2, %3" : "=v"(d) : "v"(a), "v"(b), "v"(c));
    return d;
}

__device__ inline unsigned short f2bf(float f) {   // round-to-nearest-even bf16
    unsigned u = __float_as_uint(f);
    u += 0x7FFFu + ((u >> 16) & 1u);
    return (unsigned short)(u >> 16);
}

__device__ inline void tsplit(float x, unsigned short& hi, unsigned short& lo) {
    unsigned u = __float_as_uint(x);
    hi = (unsigned short)(u >> 16);
    float d = x - __uint_as_float(u & 0xFFFF0000u);
    lo = (unsigned short)(__float_as_uint(d) >> 16);
}

// ---------------- setup: conv1 prepack (blocks 0..255) + sqnorm (blocks 256..287) ----
__global__ __launch_bounds__(256)
void setup_kernel(const float* __restrict__ x, float* __restrict__ sq,
                  unsigned short* __restrict__ Xhi, unsigned short* __restrict__ Xlo,
                  unsigned short* __restrict__ Yhi, unsigned short* __restrict__ Ylo) {
    const int b = blockIdx.x;
    if (b < 256) {
        int t = (b * 256 + threadIdx.x) * 2;      // over NPTS*16
        int n = t >> 4, k = t & 15;
        float xv[2];
        xv[0] = (k < 3) ? x[(size_t)n * 3 + k] : 0.f;
        xv[1] = (k + 1 < 3) ? x[(size_t)n * 3 + k + 1] : 0.f;
        ushort2 hx, lx, hy, ly;
        unsigned short* hxp = (unsigned short*)&hx;
        unsigned short* lxp = (unsigned short*)&lx;
        unsigned short* hyp = (unsigned short*)&hy;
        unsigned short* lyp = (unsigned short*)&ly;
        #pragma unroll
        for (int e = 0; e < 2; ++e) {
            float xx = xv[e];
            unsigned short hi = f2bf(xx);
            float hif = __uint_as_float((unsigned)hi << 16);
            unsigned short lo = f2bf(xx - hif);
            float y = -2.f * xx;
            unsigned short yhi = f2bf(y);
            float yhif = __uint_as_float((unsigned)yhi << 16);
            unsigned short ylo = f2bf(y - yhif);
            hxp[e] = hi; lxp[e] = lo; hyp[e] = yhi; lyp[e] = ylo;
        }
        *(ushort2*)&Xhi[t] = hx;
        *(ushort2*)&Xlo[t] = lx;
        *(ushort2*)&Yhi[t] = hy;
        *(ushort2*)&Ylo[t] = ly;
    } else {
        int n = (b - 256) * 256 + threadIdx.x;
        float a = x[(size_t)n * 3], bb = x[(size_t)n * 3 + 1], c = x[(size_t)n * 3 + 2];
        sq[n] = fmaf(a, a, fmaf(bb, bb, c * c));
    }
}

// ---------------- fused W prepack: W[K][N] fp32 -> [N][K] split-bf16, 3 matrices ----
__global__ __launch_bounds__(256)
void wprep_kernel(const float* __restrict__ Wl, const float* __restrict__ Wm1,
                  const float* __restrict__ Wm2,
                  unsigned short* __restrict__ WlT_hi, unsigned short* __restrict__ WlT_lo,
                  unsigned short* __restrict__ Wm1T_hi, unsigned short* __restrict__ Wm1T_lo,
                  unsigned short* __restrict__ Wm2T_hi, unsigned short* __restrict__ Wm2T_lo) {
    const int b = blockIdx.x;
    const float* W; unsigned short *Thi, *Tlo; int t, K, nmask, nbits;
    if (b < 768)       { W = Wl;  Thi = WlT_hi;  Tlo = WlT_lo;  t = b * 256 + threadIdx.x;          K = 192;  nbits = 10; }
    else if (b < 1792) { W = Wm1; Thi = Wm1T_hi; Tlo = Wm1T_lo; t = (b - 768) * 256 + threadIdx.x;  K = 1024; nbits = 8; }
    else               { W = Wm2; Thi = Wm2T_hi; Tlo = Wm2T_lo; t = (b - 1792) * 256 + threadIdx.x; K = 256;  nbits = 7; }
    nmask = (1 << nbits) - 1;
    int k = t >> nbits, n = t & nmask;
    float xx = W[t];
    unsigned short hi = f2bf(xx);
    float hif = __uint_as_float((unsigned)hi << 16);
    unsigned short lo = f2bf(xx - hif);
    Thi[(size_t)n * K + k] = hi;
    Tlo[(size_t)n * K + k] = lo;
}

// sorted-insert network, depth KPART, on a NAMED key (rule #20: no address-taking)
#define NETP(key)                                                              \
    do {                                                                       \
        _Pragma("unroll")                                                      \
        for (int p = KPART - 1; p >= 1; --p)                                   \
            top[p] = umed3(key, top[p - 1], top[p]);                           \
        top[0] = min(top[0], key);                                             \
    } while (0)

// candidate processing (self-exclusion branchless, per r10 — hoisting was null)
#define PROCESS(Cv, j0base)                                                    \
    do {                                                                       \
        _Pragma("unroll")                                                      \
        for (int q = 0; q < 4; ++q) {                                          \
            _Pragma("unroll")                                                  \
            for (int t = 0; t < 4; ++t) {                                      \
                const int j = (j0base) + h * 4 + q * 8 + t;                    \
                float dd = fmaxf((Cv)[q * 4 + t], 0.f);                        \
                unsigned key = (__float_as_uint(dd) & 0xFFFFE000u) | (unsigned)j; \
                if (j == bi) key = 0xFFFFFFFFu;                                \
                NETP(key);                                                     \
            }                                                                  \
        }                                                                      \
    } while (0)

// ---------------- kNN phase A via MFMA, software-pipelined (r10 structure, K=12 lists) ----
template<int KP>
__global__ __launch_bounds__(256, 2)
void knnA_mfma(const unsigned short* __restrict__ Yhi, const unsigned short* __restrict__ Ylo,
               const unsigned short* __restrict__ Xhi, const unsigned short* __restrict__ Xlo,
               const float* __restrict__ sq, unsigned int* __restrict__ part) {
    constexpr int NS = KP / 16;
    constexpr int NT = 8;
    const int wave = threadIdx.x >> 6, lane = threadIdx.x & 63;
    const int col = lane & 31;
    const int h   = lane >> 5;
    const int bi  = (blockIdx.x * 4 + wave) * 32 + col;
    const int jbase = blockIdx.y * 256;

    bf16x8 bhi[NS], blo[NS];
    #pragma unroll
    for (int s = 0; s < NS; ++s) {
        bhi[s] = *(const bf16x8*)&Xhi[(size_t)bi * KP + s * 16 + h * 8];
        blo[s] = *(const bf16x8*)&Xlo[(size_t)bi * KP + s * 16 + h * 8];
    }
    const float sqi = sq[bi];

    unsigned top[KPART];
    #pragma unroll
    for (int k = 0; k < KPART; ++k) top[k] = 0xFFFFFFFFu;

    bf16x8 fA[NS], fB[NS], lo[NS];
    f32x16 CCa, CCb;

    {
        const size_t a0 = (size_t)(jbase + col) * KP + h * 8;
        #pragma unroll
        for (int s = 0; s < NS; ++s)
            fA[s] = *(const bf16x8*)&Yhi[a0 + s * 16];
    }

    #pragma unroll 1
    for (int jt2 = 0; jt2 < NT; jt2 += 2) {
        const int j0 = jbase + jt2 * 32;
        const int aj = j0 + col;

        #pragma unroll
        for (int s = 0; s < NS; ++s)
            fB[s] = *(const bf16x8*)&Yhi[(size_t)(aj + 32) * KP + s * 16 + h * 8];
        #pragma unroll
        for (int s = 0; s < NS; ++s)
            lo[s] = *(const bf16x8*)&Ylo[(size_t)aj * KP + s * 16 + h * 8];
        float4 e0 = *(const float4*)&sq[j0 + h * 4];
        float4 e1 = *(const float4*)&sq[j0 + h * 4 + 8];
        float4 e2 = *(const float4*)&sq[j0 + h * 4 + 16];
        float4 e3 = *(const float4*)&sq[j0 + h * 4 + 24];

        if (jt2 > 0) PROCESS(CCb, j0 - 32);

        CCa[0] = sqi + e0.x; CCa[1] = sqi + e0.y; CCa[2]  = sqi + e0.z; CCa[3]  = sqi + e0.w;
        CCa[4] = sqi + e1.x; CCa[5] = sqi + e1.y; CCa[6]  = sqi + e1.z; CCa[7]  = sqi + e1.w;
        CCa[8] = sqi + e2.x; CCa[9] = sqi + e2.y; CCa[10] = sqi + e2.z; CCa[11] = sqi + e2.w;
        CCa[12] = sqi + e3.x; CCa[13] = sqi + e3.y; CCa[14] = sqi + e3.z; CCa[15] = sqi + e3.w;
        #pragma unroll
        for (int s = 0; s < NS; ++s) {
            CCa = __builtin_amdgcn_mfma_f32_32x32x16_bf16(fA[s], bhi[s], CCa, 0, 0, 0);
            CCa = __builtin_amdgcn_mfma_f32_32x32x16_bf16(fA[s], blo[s], CCa, 0, 0, 0);
            CCa = __builtin_amdgcn_mfma_f32_32x32x16_bf16(lo[s], bhi[s], CCa, 0, 0, 0);
        }

        if (jt2 + 2 < NT) {
            #pragma unroll
            for (int s = 0; s < NS; ++s)
                fA[s] = *(const bf16x8*)&Yhi[(size_t)(aj + 64) * KP + s * 16 + h * 8];
        }
        #pragma unroll
        for (int s = 0; s < NS; ++s)
            lo[s] = *(const bf16x8*)&Ylo[(size_t)(aj + 32) * KP + s * 16 + h * 8];
        float4 o0 = *(const float4*)&sq[j0 + 32 + h * 4];
        float4 o1 = *(const float4*)&sq[j0 + 32 + h * 4 + 8];
        float4 o2 = *(const float4*)&sq[j0 + 32 + h * 4 + 16];
        float4 o3 = *(const float4*)&sq[j0 + 32 + h * 4 + 24];

        PROCESS(CCa, j0);

        CCb[0] = sqi + o0.x; CCb[1] = sqi + o0.y; CCb[2]  = sqi + o0.z; CCb[3]  = sqi + o0.w;
        CCb[4] = sqi + o1.x; CCb[5] = sqi + o1.y; CCb[6]  = sqi + o1.z; CCb[7]  = sqi + o1.w;
        CCb[8] = sqi + o2.x; CCb[9] = sqi + o2.y; CCb[10] = sqi + o2.z; CCb[11] = sqi + o2.w;
        CCb[12] = sqi + o3.x; CCb[13] = sqi + o3.y; CCb[14] = sqi + o3.z; CCb[15] = sqi + o3.w;
        #pragma unroll
        for (int s = 0; s < NS; ++s) {
            CCb = __builtin_amdgcn_mfma_f32_32x32x16_bf16(fB[s], bhi[s], CCb, 0, 0, 0);
            CCb = __builtin_amdgcn_mfma_f32_32x32x16_bf16(fB[s], blo[s], CCb, 0, 0, 0);
            CCb = __builtin_amdgcn_mfma_f32_32x32x16_bf16(lo[s], bhi[s], CCb, 0, 0, 0);
        }
    }
    PROCESS(CCb, jbase + (NT - 1) * 32);

    // merge the two h-half lists (partner lane = lane ^ 32), keep lowest KPART
    {
        bool done = false;
        #pragma unroll
        for (int k = 0; k < KPART; ++k) {
            unsigned c = __shfl_xor(top[k], 32);
            if (!done) done = __all(c >= top[KPART - 1]);
            if (!done) NETP(c);
        }
    }

    if (h == 0) {
        unsigned* o = part + ((size_t)bi * NLISTS + blockIdx.y) * KPART;
        #pragma unroll
        for (int k = 0; k < KPART; ++k) o[k] = top[k];
    }
}

// ---------------- fused kNN phase B (blocks 0..1023) + featAB (blocks 1024..3071) ----
// Phase B: lane holds list l (12 entries + 8 sentinels in a 20-slot register list);
// 5-level shfl_xor butterfly produces the exact global top-20 per row.
template<int D>
__global__ __launch_bounds__(256)
void knnBfeat_kernel(const unsigned int* __restrict__ part, int* __restrict__ idx_out,
                     const float* __restrict__ X, int stride, const float* __restrict__ W,
                     float* __restrict__ A, float* __restrict__ B) {
    const int wave = threadIdx.x >> 6, lane = threadIdx.x & 63;
    if (blockIdx.x < 1024) {
        const int half = lane >> 5;
        const int l = lane & 31;
        const int row = (blockIdx.x * 4 + wave) * 2 + half;

        unsigned top[KNN];
        const unsigned* p = part + ((size_t)row * NLISTS + l) * KPART;
        #pragma unroll
        for (int k = 0; k < KPART; k += 4) {
            uint4 v = *(const uint4*)(p + k);
            top[k] = v.x; top[k + 1] = v.y; top[k + 2] = v.z; top[k + 3] = v.w;
        }
        #pragma unroll
        for (int k = KPART; k < KNN; ++k) top[k] = 0xFFFFFFFFu;

        #pragma unroll
        for (int mi = 0; mi < 5; ++mi) {
            const int m = 1 << mi;
            bool done = false;
            #pragma unroll
            for (int k = 0; k < KNN; ++k) {
                unsigned c = __shfl_xor(top[k], m);
                if (!done) done = __all(c >= top[KNN - 1]);
                if (!done) {
                    #pragma unroll
                    for (int q = KNN - 1; q >= 1; --q)
                        top[q] = umed3(c, top[q - 1], top[q]);
                    top[0] = min(top[0], c);
                }
            }
        }

        if (l == 0) {
            #pragma unroll
            for (int k = 0; k < KNN; ++k)
                idx_out[(size_t)row * KNN + k] = (int)(top[k] & 0x1FFFu);
        }
    } else {
        const int n = (blockIdx.x - 1024) * 4 + wave;
        float a = 0.f, b = 0.f;
        const float* xp = X + (size_t)n * stride;
        #pragma unroll
        for (int f = 0; f < D; ++f) {
            float xf = xp[f];
            a = fmaf(xf, W[(size_t)f * 64 + lane], a);
            b = fmaf(xf, W[(size_t)(D + f) * 64 + lane], b);
        }
        A[(size_t)n * 64 + lane] = a;
        B[(size_t)n * 64 + lane] = b;
    }
}

// ---------------- fused edge aggregation (+cat split stripe) [+sqnorm+knn packs] ----
template<bool PACKS>
__global__ __launch_bounds__(256)
void edge_fuse_kernel(const float* __restrict__ A, const float* __restrict__ B,
                      const int* __restrict__ idx, const float* __restrict__ bias,
                      float* __restrict__ out, int colofs,
                      unsigned short* __restrict__ catHi, unsigned short* __restrict__ catLo,
                      float* __restrict__ sqo,
                      unsigned short* __restrict__ Xhi, unsigned short* __restrict__ Xlo,
                      unsigned short* __restrict__ Yhi, unsigned short* __restrict__ Ylo) {
    const int wave = threadIdx.x >> 6, lane = threadIdx.x & 63;
    const int n = blockIdx.x * 4 + wave;
    const float base = A[(size_t)n * 64 + lane] - B[(size_t)n * 64 + lane] + bias[lane];
    float m = -INFINITY;
    #pragma unroll 4
    for (int k = 0; k < KNN; ++k) {
        int j = idx[(size_t)n * KNN + k];
        m = fmaxf(m, base + B[(size_t)j * 64 + lane]);
    }
    m = fmaxf(m, 0.f);
    if constexpr (PACKS) out[(size_t)n * 192 + colofs + lane] = m;  // fp32 cat only read by next conv

    unsigned short chi, clo;
    tsplit(m, chi, clo);
    catHi[(size_t)n * 192 + colofs + lane] = chi;
    catLo[(size_t)n * 192 + colofs + lane] = clo;

    if constexpr (PACKS) {
        float s = m * m;
        #pragma unroll
        for (int off = 32; off; off >>= 1) s += __shfl_xor(s, off);
        if (lane == 0) sqo[n] = s;

        unsigned short hi = f2bf(m);
        float hif = __uint_as_float((unsigned)hi << 16);
        unsigned short lo = f2bf(m - hif);
        float y = -2.f * m;
        unsigned short yhi = f2bf(y);
        float yhif = __uint_as_float((unsigned)yhi << 16);
        unsigned short ylo = f2bf(y - yhif);
        Xhi[(size_t)n * 64 + lane] = hi;
        Xlo[(size_t)n * 64 + lane] = lo;
        Yhi[(size_t)n * 64 + lane] = yhi;
        Ylo[(size_t)n * 64 + lane] = ylo;
    }
}

// ---------------- MFMA GEMM + bias + relu, pre-split operands ----------------
template<int K, int N, int CTW, bool SPLIT_OUT>
__global__ __launch_bounds__(256, 3)
void gemm_mfma(const unsigned short* __restrict__ Ahi, const unsigned short* __restrict__ Alo,
               const unsigned short* __restrict__ Whi, const unsigned short* __restrict__ Wlo,
               const float* __restrict__ bias, float* __restrict__ C,
               unsigned short* __restrict__ Chi, unsigned short* __restrict__ Clo) {
    const int wave = threadIdx.x >> 6, lane = threadIdx.x & 63;
    const int col = lane & 31, h = lane >> 5;
    const int r0 = blockIdx.x * 32;
    const int nb = blockIdx.y * (CTW * 128) + wave * (CTW * 32);
    const size_t abase = (size_t)(r0 + col) * K + h * 8;

    f32x16 acc[CTW];
    #pragma unroll
    for (int c = 0; c < CTW; ++c)
        #pragma unroll
        for (int r = 0; r < 16; ++r) acc[c][r] = 0.f;

    #pragma unroll 4
    for (int s = 0; s < K / 16; ++s) {
        bf16x8 ahi = *(const bf16x8*)&Ahi[abase + s * 16];
        bf16x8 alo = *(const bf16x8*)&Alo[abase + s * 16];
        #pragma unroll
        for (int c = 0; c < CTW; ++c) {
            const size_t wb = (size_t)(nb + c * 32 + col) * K + s * 16 + h * 8;
            bf16x8 bhi = *(const bf16x8*)&Whi[wb];
            bf16x8 blo = *(const bf16x8*)&Wlo[wb];
            acc[c] = __builtin_amdgcn_mfma_f32_32x32x16_bf16(ahi, bhi, acc[c], 0, 0, 0);
            acc[c] = __builtin_amdgcn_mfma_f32_32x32x16_bf16(alo, bhi, acc[c], 0, 0, 0);
            acc[c] = __builtin_amdgcn_mfma_f32_32x32x16_bf16(ahi, blo, acc[c], 0, 0, 0);
        }
    }

    #pragma unroll
    for (int c = 0; c < CTW; ++c) {
        const int n = nb + c * 32 + col;
        const float b = bias[n];
        #pragma unroll
        for (int q = 0; q < 4; ++q)
            #pragma unroll
            for (int t = 0; t < 4; ++t) {
                const int rl = 4 * h + 8 * q + t;
                float v = fmaxf(acc[c][q * 4 + t] + b, 0.f);
                if constexpr (SPLIT_OUT) {
                    unsigned short vh, vl;
                    tsplit(v, vh, vl);
                    Chi[(size_t)(r0 + rl) * N + n] = vh;
                    Clo[(size_t)(r0 + rl) * N + n] = vl;
                } else {
                    C[(size_t)(r0 + rl) * N + n] = v;
                }
            }
    }
}

// ---------------- final FC (128->50) + log_softmax ----------------
__global__ __launch_bounds__(256)
void final_kernel(const float* __restrict__ H, const float* __restrict__ Wo,
                  const float* __restrict__ bo, float* __restrict__ out) {
    const int wave = threadIdx.x >> 6, lane = threadIdx.x & 63;
    const int n = blockIdx.x * 4 + wave;
    float v = -INFINITY;
    if (lane < 50) {
        float a = bo[lane];
        const float* h = H + (size_t)n * 128;
        #pragma unroll 4
        for (int f = 0; f < 128; ++f) a = fmaf(h[f], Wo[f * 50 + lane], a);
        v = a;
    }
    float mx = v;
    #pragma unroll
    for (int off = 32; off; off >>= 1) mx = fmaxf(mx, __shfl_xor(mx, off));
    float e = (lane < 50) ? expf(v - mx) : 0.f;
    float s = e;
    #pragma unroll
    for (int off = 32; off; off >>= 1) s += __shfl_xor(s, off);
    if (lane < 50) out[(size_t)n * 50 + lane] = v - mx - logf(s);
}

extern "C" void kernel_launch(void* const* d_in, const int* in_sizes, int n_in,
                              void* d_out, int out_size, void* d_ws, size_t ws_size,
                              hipStream_t stream) {
    const float* x   = (const float*)d_in[0];
    const float* W1  = (const float*)d_in[1];
    const float* b1  = (const float*)d_in[2];
    const float* W2  = (const float*)d_in[3];
    const float* b2  = (const float*)d_in[4];
    const float* W3  = (const float*)d_in[5];
    const float* b3  = (const float*)d_in[6];
    const float* Wl  = (const float*)d_in[7];
    const float* bl  = (const float*)d_in[8];
    const float* Wm1 = (const float*)d_in[9];
    const float* bm1 = (const float*)d_in[10];
    const float* Wm2 = (const float*)d_in[11];
    const float* bm2 = (const float*)d_in[12];
    const float* Wo  = (const float*)d_in[13];
    const float* bo  = (const float*)d_in[14];

    float* ws   = (float*)d_ws;
    float* sq   = ws + OFF_SQ;
    int*   idx  = (int*)(ws + OFF_IDX);
    float* Abuf = ws + OFF_A;
    float* Bbuf = ws + OFF_B;
    float* cat  = ws + OFF_CAT;
    unsigned int* part = (unsigned int*)(ws + OFF_PART);
    unsigned short* Phi = (unsigned short*)(ws + OFF_PACK);
    unsigned short* Plo = (unsigned short*)(ws + OFF_PACK + PACK_ELEMS);
    unsigned short* Qhi = (unsigned short*)(ws + OFF_PACK + 2 * PACK_ELEMS);
    unsigned short* Qlo = (unsigned short*)(ws + OFF_PACK + 3 * PACK_ELEMS);
    unsigned short* h1hi = (unsigned short*)(ws + OFF_H1);
    unsigned short* h1lo = (unsigned short*)(ws + OFF_H1 + 4194304);
    unsigned short* catHi = (unsigned short*)(ws + OFF_H2);
    unsigned short* catLo = (unsigned short*)(ws + OFF_H2 + 786432);
    unsigned short* h2hi = (unsigned short*)(ws + OFF_H2);          // written after catXX dead
    unsigned short* h2lo = (unsigned short*)(ws + OFF_H2 + 1048576);
    float* h3   = ws + OFF_H3;
    unsigned short* WlT_hi  = (unsigned short*)(ws + OFF_WT);
    unsigned short* WlT_lo  = (unsigned short*)(ws + OFF_WT + 98304);
    unsigned short* Wm1T_hi = (unsigned short*)(ws + OFF_WT + 196608);
    unsigned short* Wm1T_lo = (unsigned short*)(ws + OFF_WT + 327680);
    unsigned short* Wm2T_hi = (unsigned short*)(ws + OFF_WT + 458752);
    unsigned short* Wm2T_lo = (unsigned short*)(ws + OFF_WT + 475136);
    float* out  = (float*)d_out;

    dim3 b256(256);
    dim3 gknn(64, 32);

    // conv1 (kNN on raw 3-D points, K padded to 16)
    setup_kernel<<<288, b256, 0, stream>>>(x, sq, Phi, Plo, Qhi, Qlo);
    knnA_mfma<16><<<gknn, b256, 0, stream>>>(Qhi, Qlo, Phi, Plo, sq, part);
    knnBfeat_kernel<3><<<3072, b256, 0, stream>>>(part, idx, x, 3, W1, Abuf, Bbuf);
    edge_fuse_kernel<true><<<2048, b256, 0, stream>>>(Abuf, Bbuf, idx, b1, cat, 0,
                                                      catHi, catLo, sq, Phi, Plo, Qhi, Qlo);

    // conv2
    knnA_mfma<64><<<gknn, b256, 0, stream>>>(Qhi, Qlo, Phi, Plo, sq, part);
    knnBfeat_kernel<64><<<3072, b256, 0, stream>>>(part, idx, cat, 192, W2, Abuf, Bbuf);
    edge_fuse_kernel<true><<<2048, b256, 0, stream>>>(Abuf, Bbuf, idx, b2, cat, 64,
                                                      catHi, catLo, sq, Phi, Plo, Qhi, Qlo);

    // conv3
    knnA_mfma<64><<<gknn, b256, 0, stream>>>(Qhi, Qlo, Phi, Plo, sq, part);
    knnBfeat_kernel<64><<<3072, b256, 0, stream>>>(part, idx, cat + 64, 192, W3, Abuf, Bbuf);
    edge_fuse_kernel<false><<<2048, b256, 0, stream>>>(Abuf, Bbuf, idx, b3, cat, 128,
                                                       catHi, catLo, nullptr,
                                                       nullptr, nullptr, nullptr, nullptr);

    // MLP head — W prepack (A-region free), then pre-split MFMA GEMMs
    wprep_kernel<<<1920, b256, 0, stream>>>(Wl, Wm1, Wm2, WlT_hi, WlT_lo,
                                            Wm1T_hi, Wm1T_lo, Wm2T_hi, Wm2T_lo);

    dim3 g1(256, 4);
    gemm_mfma<192, 1024, 2, true><<<g1, b256, 0, stream>>>(catHi, catLo, WlT_hi, WlT_lo,
                                                           bl, nullptr, h1hi, h1lo);
    dim3 g2(256, 2);
    gemm_mfma<1024, 256, 1, true><<<g2, b256, 0, stream>>>(h1hi, h1lo, Wm1T_hi, Wm1T_lo,
                                                           bm1, nullptr, h2hi, h2lo);
    dim3 g3(256, 1);
    gemm_mfma<256, 128, 1, false><<<g3, b256, 0, stream>>>(h2hi, h2lo, Wm2T_hi, Wm2T_lo,
                                                           bm2, h3, nullptr, nullptr);
    final_kernel<<<2048, b256, 0, stream>>>(h3, Wo, bo, out);
}